// Round 9
// baseline (112.658 us; speedup 1.0000x reference)
//
#include <hip/hip_runtime.h>
#include <hip/hip_bf16.h>

// Dense softmax attention (NO 1/sqrt(D) scale). B=4, L=2048, H=8, D=64,
// fp32 in/out, layout (B, L, H, D).
// Round 8: LDS double-buffer + ONE barrier/tile + paired-V^T b128 reads.
//  - Loop body: ds_reads(buf t) FIRST -> writeKV(buf t+1) -> issue(t+3)
//    -> QK/exp/PV -> barrier. Staging drains under compute; reads(t) are
//    lgkm-drained by barrier(t) before iter t+1 overwrites buf[t&1].
//  - V^T stored with permuted key positions (pos = lg*8+kg*4+r within each
//    32-key half) so one bf16x8 read serves both kg PV fragments: 8 b64 ->
//    4 b128 per wave-tile.
//  - Everything else from round 7 (passed, 0.03125): K16 PV direct-feed,
//    f16 QK^T swapped mfma(K,Q), log2e in Q, exp2, ones-MFMA lsum,
//    4 qsub x 2 ks waves, 512 thr, XCD swizzle, exact k-split merge.

#define B_ 4
#define L_ 2048
#define H_ 8
#define D_ 64
#define RST_ 512               // floats between consecutive l (H_*D_)
#define QW_ 32
#define QB_ 128                // 4 q-subs * 32 rows
#define KT_ 64
#define NT_ (L_ / KT_)         // 32
#define RS_ 88                 // K/V LDS row stride, 2B units (176B)
#define OTS_ 68                // epilogue transpose row stride, f32
#define SCW_ 35                // merge scratch words/lane
#define LOG2E_ 1.44269504088896f

// smem: Kf[2] at 0 / 11264 ; Vt[2] at 22528 / 33792 ; total 45056
//       epilogue overlay: Sc[4][64][SCW_] f32 = 35840B; Ot[w<4] at w*8960
#define SMEM_BYTES 45056

typedef _Float16 f16x8 __attribute__((ext_vector_type(8)));
typedef short    s16x4 __attribute__((ext_vector_type(4)));
typedef short    s16x8 __attribute__((ext_vector_type(8)));
typedef float    f32x4 __attribute__((ext_vector_type(4)));

__device__ __forceinline__ unsigned pk_bf16(float a, float b) {
    const __bf16 x = (__bf16)a, y = (__bf16)b;
    return ((unsigned)__builtin_bit_cast(unsigned short, y) << 16) |
           (unsigned)__builtin_bit_cast(unsigned short, x);
}

__device__ __forceinline__ f32x4 mfma16_bf16(s16x4 a, s16x4 b, f32x4 c) {
    return __builtin_amdgcn_mfma_f32_16x16x16bf16_1k(a, b, c, 0, 0, 0);
}

struct Stage { float4 k0, k1, v0, v1; };

__global__ __launch_bounds__(512, 4) void attn_dbuf1b(
    const float* __restrict__ Qg, const float* __restrict__ Kg,
    const float* __restrict__ Vg, float* __restrict__ Og)
{
    __shared__ __align__(16) char smem[SMEM_BYTES];
    _Float16* Kf0 = (_Float16*)smem;
    _Float16* Kf1 = (_Float16*)(smem + 11264);
    __bf16*   Vt0 = (__bf16*)(smem + 22528);
    __bf16*   Vt1 = (__bf16*)(smem + 33792);
    float*    Sc  = (float*)smem;                   // epilogue overlay

    const int tid  = threadIdx.x;
    const int w    = tid >> 6;         // 0..7
    const int qsub = w & 3;
    const int ks   = w >> 2;           // key-half 0/1
    const int ln   = tid & 15;
    const int lg   = (tid >> 4) & 3;

    // XCD-aware bijective swizzle (512 % 8 == 0)
    const int blk   = (blockIdx.x & 7) * 64 + (blockIdx.x >> 3);
    const int qtile = blk & (L_ / QB_ - 1);
    const int bh    = blk >> 4;
    const int h     = bh & (H_ - 1);
    const int b     = bh >> 3;

    const size_t bhbase = (size_t)b * (L_ * H_ * D_) + (size_t)h * D_;
    const int    qbase  = qtile * QB_ + qsub * QW_;

    // ---- Q fragments f16, pre-scaled by log2e ----
    f16x8 qf[2][2];
#pragma unroll
    for (int ms = 0; ms < 2; ++ms) {
#pragma unroll
        for (int dc = 0; dc < 2; ++dc) {
            const float* src = Qg + bhbase
                + (size_t)(qbase + ms * 16 + ln) * RST_ + dc * 32 + lg * 8;
            const float4 a = ((const float4*)src)[0];
            const float4 c = ((const float4*)src)[1];
            f16x8 f;
            f[0] = (_Float16)(a.x * LOG2E_); f[1] = (_Float16)(a.y * LOG2E_);
            f[2] = (_Float16)(a.z * LOG2E_); f[3] = (_Float16)(a.w * LOG2E_);
            f[4] = (_Float16)(c.x * LOG2E_); f[5] = (_Float16)(c.y * LOG2E_);
            f[6] = (_Float16)(c.z * LOG2E_); f[7] = (_Float16)(c.w * LOG2E_);
            qf[ms][dc] = f;
        }
    }

    f32x4 o[2][4];          // O^T partial: lane holds d=dg*16+lg*4+r, q=ln
    f32x4 lsum[2];
#pragma unroll
    for (int ms = 0; ms < 2; ++ms) {
        lsum[ms] = (f32x4){0.f, 0.f, 0.f, 0.f};
#pragma unroll
        for (int dg = 0; dg < 4; ++dg) o[ms][dg] = (f32x4){0.f, 0.f, 0.f, 0.f};
    }

    s16x4 ones4;
#pragma unroll
    for (int j = 0; j < 4; ++j) ones4[j] = (short)0x3F80;   // bf16 1.0

    // ---- staging mappings ----
    const int krow = tid >> 3;            // 0..63
    const int kd8  = (tid & 7) * 8;       // 0..56
    const int vkp  = (tid & 31) * 2;      // key pair base 0..62
    const int vdb  = (tid >> 5) * 4;      // d base 0..60
    // permuted V^T position: k = (k&32) | kg*16 + lg*4 + r  ->  pos = (k&32) | lg*8 + kg*4 + r
    const int vpos = (vkp & 32) + (((vkp & 15) >> 2) * 8) + (((vkp >> 4) & 1) * 4) + (vkp & 3);

    const float* kpA = Kg + bhbase + (size_t)krow * RST_ + kd8;
    const float* vpA = Vg + bhbase + (size_t)vkp * RST_ + vdb;
    const float* kpB = kpA + (size_t)KT_ * RST_;
    const float* vpB = vpA + (size_t)KT_ * RST_;

    Stage sA, sB;

    auto issueS = [&](Stage& s, const float*& kp, const float*& vp) {
        s.k0 = ((const float4*)kp)[0];
        s.k1 = ((const float4*)kp)[1];
        s.v0 = ((const float4*)vp)[0];
        s.v1 = ((const float4*)(vp + RST_))[0];
        kp += (size_t)2 * KT_ * RST_;      // two tiles ahead per set
        vp += (size_t)2 * KT_ * RST_;
    };
    auto writeKV = [&](_Float16* Kf, __bf16* Vt, const Stage& s) {
        f16x8 kw;
        kw[0] = (_Float16)s.k0.x; kw[1] = (_Float16)s.k0.y;
        kw[2] = (_Float16)s.k0.z; kw[3] = (_Float16)s.k0.w;
        kw[4] = (_Float16)s.k1.x; kw[5] = (_Float16)s.k1.y;
        kw[6] = (_Float16)s.k1.z; kw[7] = (_Float16)s.k1.w;
        *(f16x8*)&Kf[krow * RS_ + kd8] = kw;
        const float av[4] = {s.v0.x, s.v0.y, s.v0.z, s.v0.w};
        const float bv[4] = {s.v1.x, s.v1.y, s.v1.z, s.v1.w};
#pragma unroll
        for (int i = 0; i < 4; ++i)
            *(unsigned*)&Vt[(vdb + i) * RS_ + vpos] = pk_bf16(av[i], bv[i]);
    };

    f16x8 kfr[2][2];
    s16x8 vfp[4];
    auto readFrags = [&](const _Float16* Kf, const __bf16* Vt) {
#pragma unroll
        for (int dc = 0; dc < 2; ++dc)
#pragma unroll
            for (int kg = 0; kg < 2; ++kg)
                kfr[dc][kg] = *(const f16x8*)
                    &Kf[(ks * 32 + kg * 16 + ln) * RS_ + dc * 32 + lg * 8];
#pragma unroll
        for (int dg = 0; dg < 4; ++dg)
            vfp[dg] = *(const s16x8*)&Vt[(dg * 16 + ln) * RS_ + ks * 32 + lg * 8];
    };

    auto computeT = [&]() {
#pragma unroll
        for (int ms = 0; ms < 2; ++ms) {
            f32x4 st[2];
#pragma unroll
            for (int kg = 0; kg < 2; ++kg) st[kg] = (f32x4){0.f, 0.f, 0.f, 0.f};
            __builtin_amdgcn_s_setprio(1);
#pragma unroll
            for (int dc = 0; dc < 2; ++dc)
#pragma unroll
                for (int kg = 0; kg < 2; ++kg)
                    st[kg] = __builtin_amdgcn_mfma_f32_16x16x32_f16(
                        kfr[dc][kg], qf[ms][dc], st[kg], 0, 0, 0);
            __builtin_amdgcn_s_setprio(0);

            s16x4 pf[2];
#pragma unroll
            for (int kg = 0; kg < 2; ++kg) {
                const float p0 = __builtin_amdgcn_exp2f(st[kg][0]);
                const float p1 = __builtin_amdgcn_exp2f(st[kg][1]);
                const float p2 = __builtin_amdgcn_exp2f(st[kg][2]);
                const float p3 = __builtin_amdgcn_exp2f(st[kg][3]);
                union { unsigned u[2]; s16x4 v; } pu;
                pu.u[0] = pk_bf16(p0, p1);
                pu.u[1] = pk_bf16(p2, p3);
                pf[kg] = pu.v;
            }

            __builtin_amdgcn_s_setprio(1);
#pragma unroll
            for (int kg = 0; kg < 2; ++kg) {
                lsum[ms] = mfma16_bf16(ones4, pf[kg], lsum[ms]);
#pragma unroll
                for (int dg = 0; dg < 4; ++dg) {
                    const s16x4 vh = (kg == 0)
                        ? __builtin_shufflevector(vfp[dg], vfp[dg], 0, 1, 2, 3)
                        : __builtin_shufflevector(vfp[dg], vfp[dg], 4, 5, 6, 7);
                    o[ms][dg] = mfma16_bf16(vh, pf[kg], o[ms][dg]);
                }
            }
            __builtin_amdgcn_s_setprio(0);
        }
    };

    // ---- prologue: tiles 0,1 issued; tile 0 written; tile 2 issued ----
    issueS(sA, kpA, vpA);       // tile 0
    issueS(sB, kpB, vpB);       // tile 1
    writeKV(Kf0, Vt0, sA);      // tile 0 -> buf0
    issueS(sA, kpA, vpA);       // tile 2
    __syncthreads();

    // ---- main loop: ONE barrier per tile ----
    for (int t = 0; t < NT_; t += 2) {
        // even tile t from buf0
        readFrags(Kf0, Vt0);
        writeKV(Kf1, Vt1, sB);                      // tile t+1 (t+1 <= 31)
        if (t + 3 < NT_) issueS(sB, kpB, vpB);      // tile t+3
        computeT();
        __syncthreads();
        // odd tile t+1 from buf1
        readFrags(Kf1, Vt1);
        if (t + 2 < NT_) writeKV(Kf0, Vt0, sA);     // tile t+2
        if (t + 4 < NT_) issueS(sA, kpA, vpA);      // tile t+4
        computeT();
        __syncthreads();
    }

    // ---- merge epilogue (2-way k-split partials add exactly) ----
    const int lane = tid & 63;
    if (w >= 4) {
        float* sc = &Sc[((w - 4) * 64 + lane) * SCW_];
#pragma unroll
        for (int ms = 0; ms < 2; ++ms)
#pragma unroll
            for (int dg = 0; dg < 4; ++dg)
#pragma unroll
                for (int r = 0; r < 4; ++r)
                    sc[ms * 16 + dg * 4 + r] = o[ms][dg][r];
        sc[32] = lsum[0][0];
        sc[33] = lsum[1][0];
    }
    __syncthreads();
    if (w < 4) {
        const float* sc = &Sc[(w * 64 + lane) * SCW_];
        float po[2][4][4];
#pragma unroll
        for (int ms = 0; ms < 2; ++ms)
#pragma unroll
            for (int dg = 0; dg < 4; ++dg)
#pragma unroll
                for (int r = 0; r < 4; ++r)
                    po[ms][dg][r] = o[ms][dg][r] + sc[ms * 16 + dg * 4 + r];
        const float linv[2] = {1.0f / (lsum[0][0] + sc[32]),
                               1.0f / (lsum[1][0] + sc[33])};

        float* Ot = (float*)(smem + w * 8960);    // wave-private, 16B-aligned
        const int qr = lane >> 2;
        const int ch = lane & 3;
#pragma unroll
        for (int ms = 0; ms < 2; ++ms) {
#pragma unroll
            for (int dg = 0; dg < 4; ++dg) {
#pragma unroll
                for (int i = 0; i < 2; ++i) {
                    float2 pr;
                    pr.x = po[ms][dg][2 * i]     * linv[ms];
                    pr.y = po[ms][dg][2 * i + 1] * linv[ms];
                    *(float2*)&Ot[ln * OTS_ + dg * 16 + lg * 4 + 2 * i] = pr;
                }
            }
#pragma unroll
            for (int p = 0; p < 4; ++p) {
                const float4 vo = *(const float4*)&Ot[qr * OTS_ + ch * 4 + p * 16];
                *(float4*)(Og + bhbase
                    + (size_t)(qbase + ms * 16 + qr) * RST_ + ch * 4 + p * 16) = vo;
            }
        }
    }
}

extern "C" void kernel_launch(void* const* d_in, const int* in_sizes, int n_in,
                              void* d_out, int out_size, void* d_ws, size_t ws_size,
                              hipStream_t stream) {
    const float* Q = (const float*)d_in[0];
    const float* K = (const float*)d_in[1];
    const float* V = (const float*)d_in[2];
    float* O = (float*)d_out;

    const int grid = B_ * H_ * (L_ / QB_);   // 512 blocks x 512 threads
    attn_dbuf1b<<<grid, 512, 0, stream>>>(Q, K, V, O);
}

// Round 10
// 63.857 us; speedup vs baseline: 1.7642x; 1.7642x over previous
//
#include <hip/hip_runtime.h>
#include <hip/hip_bf16.h>

// Dense softmax attention (NO 1/sqrt(D) scale). B=4, L=2048, H=8, D=64,
// fp32 in/out, layout (B, L, H, D).
// Round 9: round-8 schedule (dbuf + ONE barrier/tile + paired-V^T b128),
// spill-proof implementation.
//  - Round 8 regressed (64->113us) because Stage structs passed by
//    reference into lambdas went to SCRATCH (WRITE_SIZE 17MB->225MB).
//    Fix: stage = named float4 scalars, single stage set, no struct refs.
//  - Loop (2x unrolled, static buffer ptrs): readFrags(buf cur) ->
//    writeKV(buf nxt) -> issue(t+2) -> compute -> barrier.
//  - Paired V^T layout: key pos within 32-half permuted to lg*8+kg*4+r so
//    one b128 read serves both kg PV fragments.
//  - Math/structure otherwise = round 7 (passed, 0.03125): K16 PV
//    direct-feed, f16 QK^T swapped mfma(K,Q), log2e in Q, exp2, ones-MFMA
//    lsum, 4 qsub x 2 ks waves, 512 thr, XCD swizzle, exact k-split merge.

#define B_ 4
#define L_ 2048
#define H_ 8
#define D_ 64
#define RST_ 512               // floats between consecutive l (H_*D_)
#define QW_ 32
#define QB_ 128                // 4 q-subs * 32 rows
#define KT_ 64
#define NT_ (L_ / KT_)         // 32
#define RS_ 88                 // K/V LDS row stride, 2B units (176B)
#define OTS_ 68                // epilogue transpose row stride, f32
#define SCW_ 35                // merge scratch words/lane
#define LOG2E_ 1.44269504088896f

// smem: Kf0 0 | Kf1 11264 | Vt0 22528 | Vt1 33792 ; total 45056
//       epilogue overlay: Sc[4][64][SCW_] f32 (35840B); Ot[w<4] at w*8960
#define SMEM_BYTES 45056

typedef _Float16 f16x8 __attribute__((ext_vector_type(8)));
typedef short    s16x4 __attribute__((ext_vector_type(4)));
typedef short    s16x8 __attribute__((ext_vector_type(8)));
typedef float    f32x4 __attribute__((ext_vector_type(4)));

__device__ __forceinline__ unsigned pk_bf16(float a, float b) {
    const __bf16 x = (__bf16)a, y = (__bf16)b;
    return ((unsigned)__builtin_bit_cast(unsigned short, y) << 16) |
           (unsigned)__builtin_bit_cast(unsigned short, x);
}

__device__ __forceinline__ f32x4 mfma16_bf16(s16x4 a, s16x4 b, f32x4 c) {
    return __builtin_amdgcn_mfma_f32_16x16x16bf16_1k(a, b, c, 0, 0, 0);
}

__global__ __launch_bounds__(512, 4) void attn_dbuf_fix(
    const float* __restrict__ Qg, const float* __restrict__ Kg,
    const float* __restrict__ Vg, float* __restrict__ Og)
{
    __shared__ __align__(16) char smem[SMEM_BYTES];
    _Float16* Kf0 = (_Float16*)smem;
    _Float16* Kf1 = (_Float16*)(smem + 11264);
    __bf16*   Vt0 = (__bf16*)(smem + 22528);
    __bf16*   Vt1 = (__bf16*)(smem + 33792);
    float*    Sc  = (float*)smem;                   // epilogue overlay

    const int tid  = threadIdx.x;
    const int w    = tid >> 6;         // 0..7
    const int qsub = w & 3;
    const int ks   = w >> 2;           // key-half 0/1
    const int ln   = tid & 15;
    const int lg   = (tid >> 4) & 3;

    // XCD-aware bijective swizzle (512 % 8 == 0)
    const int blk   = (blockIdx.x & 7) * 64 + (blockIdx.x >> 3);
    const int qtile = blk & (L_ / QB_ - 1);
    const int bh    = blk >> 4;
    const int h     = bh & (H_ - 1);
    const int b     = bh >> 3;

    const size_t bhbase = (size_t)b * (L_ * H_ * D_) + (size_t)h * D_;
    const int    qbase  = qtile * QB_ + qsub * QW_;

    // ---- Q fragments f16, pre-scaled by log2e ----
    f16x8 qf[2][2];
#pragma unroll
    for (int ms = 0; ms < 2; ++ms) {
#pragma unroll
        for (int dc = 0; dc < 2; ++dc) {
            const float* src = Qg + bhbase
                + (size_t)(qbase + ms * 16 + ln) * RST_ + dc * 32 + lg * 8;
            const float4 a = ((const float4*)src)[0];
            const float4 c = ((const float4*)src)[1];
            f16x8 f;
            f[0] = (_Float16)(a.x * LOG2E_); f[1] = (_Float16)(a.y * LOG2E_);
            f[2] = (_Float16)(a.z * LOG2E_); f[3] = (_Float16)(a.w * LOG2E_);
            f[4] = (_Float16)(c.x * LOG2E_); f[5] = (_Float16)(c.y * LOG2E_);
            f[6] = (_Float16)(c.z * LOG2E_); f[7] = (_Float16)(c.w * LOG2E_);
            qf[ms][dc] = f;
        }
    }

    f32x4 o[2][4];          // O^T partial: lane holds d=dg*16+lg*4+r, q=ln
    f32x4 lsum[2];
#pragma unroll
    for (int ms = 0; ms < 2; ++ms) {
        lsum[ms] = (f32x4){0.f, 0.f, 0.f, 0.f};
#pragma unroll
        for (int dg = 0; dg < 4; ++dg) o[ms][dg] = (f32x4){0.f, 0.f, 0.f, 0.f};
    }

    s16x4 ones4;
#pragma unroll
    for (int j = 0; j < 4; ++j) ones4[j] = (short)0x3F80;   // bf16 1.0

    // ---- staging mappings ----
    const int krow = tid >> 3;            // 0..63
    const int kd8  = (tid & 7) * 8;       // 0..56
    const int vkp  = (tid & 31) * 2;      // key pair base 0..62 (even)
    const int vdb  = (tid >> 5) * 4;      // d base 0..60
    // permuted V^T pos: k -> (k&32) | lg*8 + kg*4 + r
    const int vpos = (vkp & 32) + (((vkp & 15) >> 2) * 8)
                   + (((vkp >> 4) & 1) * 4) + (vkp & 3);

    const float* kp = Kg + bhbase + (size_t)krow * RST_ + kd8;
    const float* vp = Vg + bhbase + (size_t)vkp * RST_ + vdb;

    // single stage set: NAMED float4 scalars (spill-proof, rule #20)
    float4 sk0, sk1, sv0, sv1;

    auto issue = [&]() {
        sk0 = ((const float4*)kp)[0];
        sk1 = ((const float4*)kp)[1];
        sv0 = ((const float4*)vp)[0];
        sv1 = ((const float4*)(vp + RST_))[0];
        kp += (size_t)KT_ * RST_;
        vp += (size_t)KT_ * RST_;
    };
    auto writeKV = [&](_Float16* Kf, __bf16* Vt) {
        f16x8 kw;
        kw[0] = (_Float16)sk0.x; kw[1] = (_Float16)sk0.y;
        kw[2] = (_Float16)sk0.z; kw[3] = (_Float16)sk0.w;
        kw[4] = (_Float16)sk1.x; kw[5] = (_Float16)sk1.y;
        kw[6] = (_Float16)sk1.z; kw[7] = (_Float16)sk1.w;
        *(f16x8*)&Kf[krow * RS_ + kd8] = kw;
        *(unsigned*)&Vt[(vdb + 0) * RS_ + vpos] = pk_bf16(sv0.x, sv1.x);
        *(unsigned*)&Vt[(vdb + 1) * RS_ + vpos] = pk_bf16(sv0.y, sv1.y);
        *(unsigned*)&Vt[(vdb + 2) * RS_ + vpos] = pk_bf16(sv0.z, sv1.z);
        *(unsigned*)&Vt[(vdb + 3) * RS_ + vpos] = pk_bf16(sv0.w, sv1.w);
    };

    f16x8 kfr[2][2];
    s16x8 vfp[4];
    auto readFrags = [&](const _Float16* Kf, const __bf16* Vt) {
#pragma unroll
        for (int dc = 0; dc < 2; ++dc)
#pragma unroll
            for (int kg = 0; kg < 2; ++kg)
                kfr[dc][kg] = *(const f16x8*)
                    &Kf[(ks * 32 + kg * 16 + ln) * RS_ + dc * 32 + lg * 8];
#pragma unroll
        for (int dg = 0; dg < 4; ++dg)
            vfp[dg] = *(const s16x8*)&Vt[(dg * 16 + ln) * RS_ + ks * 32 + lg * 8];
    };

    auto computeT = [&]() {
#pragma unroll
        for (int ms = 0; ms < 2; ++ms) {
            f32x4 st[2];
#pragma unroll
            for (int kg = 0; kg < 2; ++kg) st[kg] = (f32x4){0.f, 0.f, 0.f, 0.f};
            __builtin_amdgcn_s_setprio(1);
#pragma unroll
            for (int dc = 0; dc < 2; ++dc)
#pragma unroll
                for (int kg = 0; kg < 2; ++kg)
                    st[kg] = __builtin_amdgcn_mfma_f32_16x16x32_f16(
                        kfr[dc][kg], qf[ms][dc], st[kg], 0, 0, 0);
            __builtin_amdgcn_s_setprio(0);

            s16x4 pf[2];
#pragma unroll
            for (int kg = 0; kg < 2; ++kg) {
                const float p0 = __builtin_amdgcn_exp2f(st[kg][0]);
                const float p1 = __builtin_amdgcn_exp2f(st[kg][1]);
                const float p2 = __builtin_amdgcn_exp2f(st[kg][2]);
                const float p3 = __builtin_amdgcn_exp2f(st[kg][3]);
                union { unsigned u[2]; s16x4 v; } pu;
                pu.u[0] = pk_bf16(p0, p1);
                pu.u[1] = pk_bf16(p2, p3);
                pf[kg] = pu.v;
            }

            __builtin_amdgcn_s_setprio(1);
#pragma unroll
            for (int kg = 0; kg < 2; ++kg) {
                lsum[ms] = mfma16_bf16(ones4, pf[kg], lsum[ms]);
#pragma unroll
                for (int dg = 0; dg < 4; ++dg) {
                    const s16x4 vh = (kg == 0)
                        ? __builtin_shufflevector(vfp[dg], vfp[dg], 0, 1, 2, 3)
                        : __builtin_shufflevector(vfp[dg], vfp[dg], 4, 5, 6, 7);
                    o[ms][dg] = mfma16_bf16(vh, pf[kg], o[ms][dg]);
                }
            }
            __builtin_amdgcn_s_setprio(0);
        }
    };

    // ---- prologue: tile0 -> buf0 (serial), tile1 staged in regs ----
    issue();                    // tile 0
    writeKV(Kf0, Vt0);
    issue();                    // tile 1 -> stage regs
    __syncthreads();

    // ---- main loop: ONE barrier per tile, 2x unrolled ----
    for (int t = 0; t < NT_; t += 2) {
        // even tile t from buf0
        readFrags(Kf0, Vt0);
        writeKV(Kf1, Vt1);                  // stage = tile t+1 (t+1 <= 31)
        if (t + 2 < NT_) issue();           // tile t+2 -> stage regs
        computeT();
        __syncthreads();
        // odd tile t+1 from buf1
        readFrags(Kf1, Vt1);
        if (t + 2 < NT_) writeKV(Kf0, Vt0); // stage = tile t+2
        if (t + 3 < NT_) issue();           // tile t+3 -> stage regs
        computeT();
        __syncthreads();
    }

    // ---- merge epilogue (2-way k-split partials add exactly) ----
    const int lane = tid & 63;
    if (w >= 4) {
        float* sc = &Sc[((w - 4) * 64 + lane) * SCW_];
#pragma unroll
        for (int ms = 0; ms < 2; ++ms)
#pragma unroll
            for (int dg = 0; dg < 4; ++dg)
#pragma unroll
                for (int r = 0; r < 4; ++r)
                    sc[ms * 16 + dg * 4 + r] = o[ms][dg][r];
        sc[32] = lsum[0][0];
        sc[33] = lsum[1][0];
    }
    __syncthreads();
    if (w < 4) {
        const float* sc = &Sc[(w * 64 + lane) * SCW_];
        float po[2][4][4];
#pragma unroll
        for (int ms = 0; ms < 2; ++ms)
#pragma unroll
            for (int dg = 0; dg < 4; ++dg)
#pragma unroll
                for (int r = 0; r < 4; ++r)
                    po[ms][dg][r] = o[ms][dg][r] + sc[ms * 16 + dg * 4 + r];
        const float linv[2] = {1.0f / (lsum[0][0] + sc[32]),
                               1.0f / (lsum[1][0] + sc[33])};

        float* Ot = (float*)(smem + w * 8960);    // wave-private, 16B-aligned
        const int qr = lane >> 2;
        const int ch = lane & 3;
#pragma unroll
        for (int ms = 0; ms < 2; ++ms) {
#pragma unroll
            for (int dg = 0; dg < 4; ++dg) {
#pragma unroll
                for (int i = 0; i < 2; ++i) {
                    float2 pr;
                    pr.x = po[ms][dg][2 * i]     * linv[ms];
                    pr.y = po[ms][dg][2 * i + 1] * linv[ms];
                    *(float2*)&Ot[ln * OTS_ + dg * 16 + lg * 4 + 2 * i] = pr;
                }
            }
#pragma unroll
            for (int p = 0; p < 4; ++p) {
                const float4 vo = *(const float4*)&Ot[qr * OTS_ + ch * 4 + p * 16];
                *(float4*)(Og + bhbase
                    + (size_t)(qbase + ms * 16 + qr) * RST_ + ch * 4 + p * 16) = vo;
            }
        }
    }
}

extern "C" void kernel_launch(void* const* d_in, const int* in_sizes, int n_in,
                              void* d_out, int out_size, void* d_ws, size_t ws_size,
                              hipStream_t stream) {
    const float* Q = (const float*)d_in[0];
    const float* K = (const float*)d_in[1];
    const float* V = (const float*)d_in[2];
    float* O = (float*)d_out;

    const int grid = B_ * H_ * (L_ / QB_);   // 512 blocks x 512 threads
    attn_dbuf_fix<<<grid, 512, 0, stream>>>(Q, K, V, O);
}

// Round 11
// 62.127 us; speedup vs baseline: 1.8134x; 1.0278x over previous
//
#include <hip/hip_runtime.h>
#include <hip/hip_bf16.h>

// Dense softmax attention (NO 1/sqrt(D) scale). B=4, L=2048, H=8, D=64,
// fp32 in/out, layout (B, L, H, D).
// Round 10: PHASE-SANDWICH ordering to break LGKM serialization.
//  - lgkmcnt is one in-order counter for ALL DS ops. Round 9's order
//    (ds_reads -> ds_writes -> MFMA-needs-reads) made the compiler's
//    lgkmcnt(0) before QK drain the staging WRITES every tile ->
//    stage and compute phases serialized (busy-sums == wall).
//  - New order: readFrags -> compute(ms=0) [waits reads only] ->
//    writeKV(next tile) -> issue(t+2) -> compute(ms=1) [register-only
//    MFMAs cover the write drain] -> barrier.
//  - compute split via macro with LITERAL ms (rule #20: static indexing).
//  - Everything else = round 9 (passed, 0.03125): K16 PV direct-feed,
//    paired-V^T b128 reads, dbuf + one barrier/tile, named-scalar stage
//    regs, f16 QK^T swapped mfma(K,Q), log2e in Q, exp2, ones-MFMA lsum,
//    4 qsub x 2 ks waves, 512 thr, XCD swizzle, exact k-split merge.

#define B_ 4
#define L_ 2048
#define H_ 8
#define D_ 64
#define RST_ 512               // floats between consecutive l (H_*D_)
#define QW_ 32
#define QB_ 128                // 4 q-subs * 32 rows
#define KT_ 64
#define NT_ (L_ / KT_)         // 32
#define RS_ 88                 // K/V LDS row stride, 2B units (176B)
#define OTS_ 68                // epilogue transpose row stride, f32
#define SCW_ 35                // merge scratch words/lane
#define LOG2E_ 1.44269504088896f

// smem: Kf0 0 | Kf1 11264 | Vt0 22528 | Vt1 33792 ; total 45056
//       epilogue overlay: Sc[4][64][SCW_] f32 (35840B); Ot[w<4] at w*8960
#define SMEM_BYTES 45056

typedef _Float16 f16x8 __attribute__((ext_vector_type(8)));
typedef short    s16x4 __attribute__((ext_vector_type(4)));
typedef short    s16x8 __attribute__((ext_vector_type(8)));
typedef float    f32x4 __attribute__((ext_vector_type(4)));

__device__ __forceinline__ unsigned pk_bf16(float a, float b) {
    const __bf16 x = (__bf16)a, y = (__bf16)b;
    return ((unsigned)__builtin_bit_cast(unsigned short, y) << 16) |
           (unsigned)__builtin_bit_cast(unsigned short, x);
}

__device__ __forceinline__ f32x4 mfma16_bf16(s16x4 a, s16x4 b, f32x4 c) {
    return __builtin_amdgcn_mfma_f32_16x16x16bf16_1k(a, b, c, 0, 0, 0);
}

// compute for one LITERAL ms value; reads kfr/vfp/qf, updates o[ms], lsum[ms]
#define COMPUTE_MS(ms)                                                         \
    do {                                                                       \
        f32x4 st0 = (f32x4){0.f, 0.f, 0.f, 0.f};                               \
        f32x4 st1 = (f32x4){0.f, 0.f, 0.f, 0.f};                               \
        __builtin_amdgcn_s_setprio(1);                                         \
        st0 = __builtin_amdgcn_mfma_f32_16x16x32_f16(kfr[0][0], qf[ms][0], st0, 0, 0, 0); \
        st1 = __builtin_amdgcn_mfma_f32_16x16x32_f16(kfr[0][1], qf[ms][0], st1, 0, 0, 0); \
        st0 = __builtin_amdgcn_mfma_f32_16x16x32_f16(kfr[1][0], qf[ms][1], st0, 0, 0, 0); \
        st1 = __builtin_amdgcn_mfma_f32_16x16x32_f16(kfr[1][1], qf[ms][1], st1, 0, 0, 0); \
        __builtin_amdgcn_s_setprio(0);                                         \
        s16x4 pf0, pf1;                                                        \
        {                                                                      \
            const float a0 = __builtin_amdgcn_exp2f(st0[0]);                   \
            const float a1 = __builtin_amdgcn_exp2f(st0[1]);                   \
            const float a2 = __builtin_amdgcn_exp2f(st0[2]);                   \
            const float a3 = __builtin_amdgcn_exp2f(st0[3]);                   \
            union { unsigned u[2]; s16x4 v; } pu;                              \
            pu.u[0] = pk_bf16(a0, a1);                                         \
            pu.u[1] = pk_bf16(a2, a3);                                         \
            pf0 = pu.v;                                                        \
            const float b0 = __builtin_amdgcn_exp2f(st1[0]);                   \
            const float b1 = __builtin_amdgcn_exp2f(st1[1]);                   \
            const float b2 = __builtin_amdgcn_exp2f(st1[2]);                   \
            const float b3 = __builtin_amdgcn_exp2f(st1[3]);                   \
            union { unsigned u[2]; s16x4 v; } pv;                              \
            pv.u[0] = pk_bf16(b0, b1);                                         \
            pv.u[1] = pk_bf16(b2, b3);                                         \
            pf1 = pv.v;                                                        \
        }                                                                      \
        __builtin_amdgcn_s_setprio(1);                                         \
        lsum[ms] = mfma16_bf16(ones4, pf0, lsum[ms]);                          \
        lsum[ms] = mfma16_bf16(ones4, pf1, lsum[ms]);                          \
        _Pragma("unroll")                                                      \
        for (int dg = 0; dg < 4; ++dg) {                                       \
            const s16x4 v0 = __builtin_shufflevector(vfp[dg], vfp[dg], 0, 1, 2, 3); \
            const s16x4 v1 = __builtin_shufflevector(vfp[dg], vfp[dg], 4, 5, 6, 7); \
            o[ms][dg] = mfma16_bf16(v0, pf0, o[ms][dg]);                       \
            o[ms][dg] = mfma16_bf16(v1, pf1, o[ms][dg]);                       \
        }                                                                      \
        __builtin_amdgcn_s_setprio(0);                                         \
    } while (0)

__global__ __launch_bounds__(512, 4) void attn_sandwich(
    const float* __restrict__ Qg, const float* __restrict__ Kg,
    const float* __restrict__ Vg, float* __restrict__ Og)
{
    __shared__ __align__(16) char smem[SMEM_BYTES];
    _Float16* Kf0 = (_Float16*)smem;
    _Float16* Kf1 = (_Float16*)(smem + 11264);
    __bf16*   Vt0 = (__bf16*)(smem + 22528);
    __bf16*   Vt1 = (__bf16*)(smem + 33792);
    float*    Sc  = (float*)smem;                   // epilogue overlay

    const int tid  = threadIdx.x;
    const int w    = tid >> 6;         // 0..7
    const int qsub = w & 3;
    const int ks   = w >> 2;           // key-half 0/1
    const int ln   = tid & 15;
    const int lg   = (tid >> 4) & 3;

    // XCD-aware bijective swizzle (512 % 8 == 0)
    const int blk   = (blockIdx.x & 7) * 64 + (blockIdx.x >> 3);
    const int qtile = blk & (L_ / QB_ - 1);
    const int bh    = blk >> 4;
    const int h     = bh & (H_ - 1);
    const int b     = bh >> 3;

    const size_t bhbase = (size_t)b * (L_ * H_ * D_) + (size_t)h * D_;
    const int    qbase  = qtile * QB_ + qsub * QW_;

    // ---- Q fragments f16, pre-scaled by log2e ----
    f16x8 qf[2][2];
#pragma unroll
    for (int ms = 0; ms < 2; ++ms) {
#pragma unroll
        for (int dc = 0; dc < 2; ++dc) {
            const float* src = Qg + bhbase
                + (size_t)(qbase + ms * 16 + ln) * RST_ + dc * 32 + lg * 8;
            const float4 a = ((const float4*)src)[0];
            const float4 c = ((const float4*)src)[1];
            f16x8 f;
            f[0] = (_Float16)(a.x * LOG2E_); f[1] = (_Float16)(a.y * LOG2E_);
            f[2] = (_Float16)(a.z * LOG2E_); f[3] = (_Float16)(a.w * LOG2E_);
            f[4] = (_Float16)(c.x * LOG2E_); f[5] = (_Float16)(c.y * LOG2E_);
            f[6] = (_Float16)(c.z * LOG2E_); f[7] = (_Float16)(c.w * LOG2E_);
            qf[ms][dc] = f;
        }
    }

    f32x4 o[2][4];          // O^T partial: lane holds d=dg*16+lg*4+r, q=ln
    f32x4 lsum[2];
#pragma unroll
    for (int ms = 0; ms < 2; ++ms) {
        lsum[ms] = (f32x4){0.f, 0.f, 0.f, 0.f};
#pragma unroll
        for (int dg = 0; dg < 4; ++dg) o[ms][dg] = (f32x4){0.f, 0.f, 0.f, 0.f};
    }

    s16x4 ones4;
#pragma unroll
    for (int j = 0; j < 4; ++j) ones4[j] = (short)0x3F80;   // bf16 1.0

    // ---- staging mappings ----
    const int krow = tid >> 3;            // 0..63
    const int kd8  = (tid & 7) * 8;       // 0..56
    const int vkp  = (tid & 31) * 2;      // key pair base 0..62 (even)
    const int vdb  = (tid >> 5) * 4;      // d base 0..60
    // permuted V^T pos: k -> (k&32) | lg*8 + kg*4 + r
    const int vpos = (vkp & 32) + (((vkp & 15) >> 2) * 8)
                   + (((vkp >> 4) & 1) * 4) + (vkp & 3);

    const float* kp = Kg + bhbase + (size_t)krow * RST_ + kd8;
    const float* vp = Vg + bhbase + (size_t)vkp * RST_ + vdb;

    // single stage set: NAMED float4 scalars (spill-proof)
    float4 sk0, sk1, sv0, sv1;

    auto issue = [&]() {
        sk0 = ((const float4*)kp)[0];
        sk1 = ((const float4*)kp)[1];
        sv0 = ((const float4*)vp)[0];
        sv1 = ((const float4*)(vp + RST_))[0];
        kp += (size_t)KT_ * RST_;
        vp += (size_t)KT_ * RST_;
    };
    auto writeKV = [&](_Float16* Kf, __bf16* Vt) {
        f16x8 kw;
        kw[0] = (_Float16)sk0.x; kw[1] = (_Float16)sk0.y;
        kw[2] = (_Float16)sk0.z; kw[3] = (_Float16)sk0.w;
        kw[4] = (_Float16)sk1.x; kw[5] = (_Float16)sk1.y;
        kw[6] = (_Float16)sk1.z; kw[7] = (_Float16)sk1.w;
        *(f16x8*)&Kf[krow * RS_ + kd8] = kw;
        *(unsigned*)&Vt[(vdb + 0) * RS_ + vpos] = pk_bf16(sv0.x, sv1.x);
        *(unsigned*)&Vt[(vdb + 1) * RS_ + vpos] = pk_bf16(sv0.y, sv1.y);
        *(unsigned*)&Vt[(vdb + 2) * RS_ + vpos] = pk_bf16(sv0.z, sv1.z);
        *(unsigned*)&Vt[(vdb + 3) * RS_ + vpos] = pk_bf16(sv0.w, sv1.w);
    };

    f16x8 kfr[2][2];
    s16x8 vfp[4];
    auto readFrags = [&](const _Float16* Kf, const __bf16* Vt) {
#pragma unroll
        for (int dc = 0; dc < 2; ++dc)
#pragma unroll
            for (int kg = 0; kg < 2; ++kg)
                kfr[dc][kg] = *(const f16x8*)
                    &Kf[(ks * 32 + kg * 16 + ln) * RS_ + dc * 32 + lg * 8];
#pragma unroll
        for (int dg = 0; dg < 4; ++dg)
            vfp[dg] = *(const s16x8*)&Vt[(dg * 16 + ln) * RS_ + ks * 32 + lg * 8];
    };

    // ---- prologue: tile0 -> buf0 (serial), tile1 staged in regs ----
    issue();                    // tile 0
    writeKV(Kf0, Vt0);
    issue();                    // tile 1 -> stage regs
    __syncthreads();

    // ---- main loop: ONE barrier/tile, phase-sandwich ordering ----
    for (int t = 0; t < NT_; t += 2) {
        // even tile t from buf0
        readFrags(Kf0, Vt0);
        COMPUTE_MS(0);                      // waits on reads ONLY (no writes issued yet)
        writeKV(Kf1, Vt1);                  // stage tile t+1; drains under MS1
        if (t + 2 < NT_) issue();           // tile t+2 -> stage regs
        COMPUTE_MS(1);                      // register-only MFMAs cover write drain
        __syncthreads();
        // odd tile t+1 from buf1
        readFrags(Kf1, Vt1);
        COMPUTE_MS(0);
        if (t + 2 < NT_) writeKV(Kf0, Vt0); // stage tile t+2
        if (t + 3 < NT_) issue();           // tile t+3 -> stage regs
        COMPUTE_MS(1);
        __syncthreads();
    }

    // ---- merge epilogue (2-way k-split partials add exactly) ----
    const int lane = tid & 63;
    if (w >= 4) {
        float* sc = &Sc[((w - 4) * 64 + lane) * SCW_];
#pragma unroll
        for (int ms = 0; ms < 2; ++ms)
#pragma unroll
            for (int dg = 0; dg < 4; ++dg)
#pragma unroll
                for (int r = 0; r < 4; ++r)
                    sc[ms * 16 + dg * 4 + r] = o[ms][dg][r];
        sc[32] = lsum[0][0];
        sc[33] = lsum[1][0];
    }
    __syncthreads();
    if (w < 4) {
        const float* sc = &Sc[(w * 64 + lane) * SCW_];
        float po[2][4][4];
#pragma unroll
        for (int ms = 0; ms < 2; ++ms)
#pragma unroll
            for (int dg = 0; dg < 4; ++dg)
#pragma unroll
                for (int r = 0; r < 4; ++r)
                    po[ms][dg][r] = o[ms][dg][r] + sc[ms * 16 + dg * 4 + r];
        const float linv[2] = {1.0f / (lsum[0][0] + sc[32]),
                               1.0f / (lsum[1][0] + sc[33])};

        float* Ot = (float*)(smem + w * 8960);    // wave-private, 16B-aligned
        const int qr = lane >> 2;
        const int ch = lane & 3;
#pragma unroll
        for (int ms = 0; ms < 2; ++ms) {
#pragma unroll
            for (int dg = 0; dg < 4; ++dg) {
#pragma unroll
                for (int i = 0; i < 2; ++i) {
                    float2 pr;
                    pr.x = po[ms][dg][2 * i]     * linv[ms];
                    pr.y = po[ms][dg][2 * i + 1] * linv[ms];
                    *(float2*)&Ot[ln * OTS_ + dg * 16 + lg * 4 + 2 * i] = pr;
                }
            }
#pragma unroll
            for (int p = 0; p < 4; ++p) {
                const float4 vo = *(const float4*)&Ot[qr * OTS_ + ch * 4 + p * 16];
                *(float4*)(Og + bhbase
                    + (size_t)(qbase + ms * 16 + qr) * RST_ + ch * 4 + p * 16) = vo;
            }
        }
    }
}

extern "C" void kernel_launch(void* const* d_in, const int* in_sizes, int n_in,
                              void* d_out, int out_size, void* d_ws, size_t ws_size,
                              hipStream_t stream) {
    const float* Q = (const float*)d_in[0];
    const float* K = (const float*)d_in[1];
    const float* V = (const float*)d_in[2];
    float* O = (float*)d_out;

    const int grid = B_ * H_ * (L_ / QB_);   // 512 blocks x 512 threads
    attn_sandwich<<<grid, 512, 0, stream>>>(Q, K, V, O);
}